// Round 12
// baseline (296.391 us; speedup 1.0000x reference)
//
#include <hip/hip_runtime.h>
#include <hip/hip_cooperative_groups.h>

namespace cg = cooperative_groups;

#define NB 4
#define NCI 64
#define NCO 64
#define PLANE 65536

// workspace offsets (floats)
#define OF_XS_RE 0
#define OF_XS_IM (OF_XS_RE + PLANE)
#define OF_O1_RE (OF_XS_IM + PLANE)
#define OF_O1_IM (OF_O1_RE + PLANE)
#define OF_O2_RE (OF_O1_IM + PLANE)
#define OF_O2_IM (OF_O2_RE + PLANE)

// stage1 LDS plane layout (within union buffer L)
#define XEOFF(w) ((w)*260)
#define XOOFF(w) (16*260 + 8 + (w)*260)

#define LDSF 11776   // union: stage1 10896 / k45 11776 floats

__global__ __launch_bounds__(1024) void mega(const float* __restrict__ x,
    const float* __restrict__ w1r, const float* __restrict__ w1i,
    const float* __restrict__ w2r, const float* __restrict__ w2i,
    float* __restrict__ ws, float* __restrict__ out) {
  __shared__ float L[LDSF];
  cg::grid_group grid = cg::this_grid();
  const int t = threadIdx.x;
  const int bid = blockIdx.x;
  const float TPF = 6.2831853071795864769f;

  // ================= phase 1: per-image 2D DFT (img = bid) =================
  {
    float* buf = L;                         // 8336 floats
    float2* s2 = (float2*)(L + 8336);       // 1024 float2
    float* cst = L + 10384;
    float* snt = L + 10640;
    const int img = bid;

    if (t < 256) {
      const float a = TPF * (float)t * (1.0f/256.0f);
      cst[t] = cosf(a);
      snt[t] = sinf(a);
    }

    const int sl = t & 3, row = t >> 2;            // staging map
    const int wq = t & 3, p = (t >> 2) & 1;        // compute map
    const int kg = (t >> 3) & 1, tr = t >> 4;
    int kyv[4];
#pragma unroll
    for (int j = 0; j < 4; ++j) kyv[j] = p + 8*kg + 2*j;

    const float* xb = x + (size_t)img * 65536;
    float4 lo = *(const float4*)(xb + row*256 + sl*4);
    float4 hi = *(const float4*)(xb + row*256 + 128 + sl*4);

    __syncthreads();                     // cst/snt ready

    float cd[4], sd[4];
#pragma unroll
    for (int j = 0; j < 4; ++j) { cd[j] = cst[kyv[j]]; sd[j] = snt[kyv[j]]; }

    float ar[4][4], ai[4][4];
#pragma unroll
    for (int j = 0; j < 4; ++j)
#pragma unroll
      for (int r = 0; r < 4; ++r) { ar[j][r] = 0.f; ai[j][r] = 0.f; }

    const int pbase = p ? (16*260 + 8) : 0;

    for (int c = 0; c < 8; ++c) {
      __syncthreads();                   // prev chunk compute done
      buf[XEOFF(sl*4+0) + row] = lo.x + hi.x;
      buf[XEOFF(sl*4+1) + row] = lo.y + hi.y;
      buf[XEOFF(sl*4+2) + row] = lo.z + hi.z;
      buf[XEOFF(sl*4+3) + row] = lo.w + hi.w;
      buf[XOOFF(sl*4+0) + row] = lo.x - hi.x;
      buf[XOOFF(sl*4+1) + row] = lo.y - hi.y;
      buf[XOOFF(sl*4+2) + row] = lo.z - hi.z;
      buf[XOOFF(sl*4+3) + row] = lo.w - hi.w;
      __syncthreads();
      if (c < 7) {                       // T14: prefetch next chunk
        const int w0n = (c+1) * 16;
        lo = *(const float4*)(xb + row*256 + w0n + sl*4);
        hi = *(const float4*)(xb + row*256 + w0n + 128 + sl*4);
      }
      float cc[4], sv[4];
#pragma unroll
      for (int j = 0; j < 4; ++j) {
        const int m = (kyv[j] * (c*16 + wq*4)) & 255;
        cc[j] = cst[m];
        sv[j] = snt[m];
      }
#pragma unroll
      for (int i = 0; i < 4; ++i) {
        const int wl = wq*4 + i;
        const float4 xs4 = *(const float4*)&buf[pbase + wl*260 + tr*4];
#pragma unroll
        for (int j = 0; j < 4; ++j) {
          ar[j][0] += xs4.x * cc[j];  ai[j][0] -= xs4.x * sv[j];
          ar[j][1] += xs4.y * cc[j];  ai[j][1] -= xs4.y * sv[j];
          ar[j][2] += xs4.z * cc[j];  ai[j][2] -= xs4.z * sv[j];
          ar[j][3] += xs4.w * cc[j];  ai[j][3] -= xs4.w * sv[j];
          const float nc = cc[j]*cd[j] - sv[j]*sd[j];
          const float ns = sv[j]*cd[j] + cc[j]*sd[j];
          cc[j] = nc; sv[j] = ns;
        }
      }
    }

    // merge w-quarters (lane bits 0..1)
#pragma unroll
    for (int j = 0; j < 4; ++j)
#pragma unroll
      for (int r = 0; r < 4; ++r) {
        ar[j][r] += __shfl_xor(ar[j][r], 1);
        ar[j][r] += __shfl_xor(ar[j][r], 2);
        ai[j][r] += __shfl_xor(ai[j][r], 1);
        ai[j][r] += __shfl_xor(ai[j][r], 2);
      }
    __syncthreads();                     // chunk-7 reads done; buf reusable
    if (wq == 0) {
#pragma unroll
      for (int j = 0; j < 4; ++j) {
        const int ky = kyv[j];
        float4 sr; sr.x = ar[j][0]; sr.y = ar[j][1]; sr.z = ar[j][2]; sr.w = ar[j][3];
        float4 si; si.x = ai[j][0]; si.y = ai[j][1]; si.z = ai[j][2]; si.w = ai[j][3];
        *(float4*)&buf[XEOFF(ky) + tr*4] = sr;
        *(float4*)&buf[XOOFF(ky) + tr*4] = si;
      }
    }
    __syncthreads();

    // part 2: h-DFT, quarter h-range per thread
    const int ky2 = t & 15, kx = (t >> 4) & 15, hh = t >> 8;
    const float cdk = cst[kx], sdk = snt[kx];
    const int m0 = (kx * hh * 64) & 255;
    float cR = cst[m0], sR = snt[m0];
    float arr = 0.f, aii = 0.f;
    const int be = XEOFF(ky2) + hh*64;
    const int bo = XOOFF(ky2) + hh*64;
#pragma unroll 4
    for (int hq = 0; hq < 16; ++hq) {
      const float4 xr = *(const float4*)&buf[be + hq*4];
      const float4 xi = *(const float4*)&buf[bo + hq*4];
      {
        arr += xr.x*cR + xi.x*sR;  aii += xi.x*cR - xr.x*sR;
        const float nc = cR*cdk - sR*sdk, ns = sR*cdk + cR*sdk; cR = nc; sR = ns;
      }
      {
        arr += xr.y*cR + xi.y*sR;  aii += xi.y*cR - xr.y*sR;
        const float nc = cR*cdk - sR*sdk, ns = sR*cdk + cR*sdk; cR = nc; sR = ns;
      }
      {
        arr += xr.z*cR + xi.z*sR;  aii += xi.z*cR - xr.z*sR;
        const float nc = cR*cdk - sR*sdk, ns = sR*cdk + cR*sdk; cR = nc; sR = ns;
      }
      {
        arr += xr.w*cR + xi.w*sR;  aii += xi.w*cR - xr.w*sR;
        const float nc = cR*cdk - sR*sdk, ns = sR*cdk + cR*sdk; cR = nc; sR = ns;
      }
    }
    s2[t].x = arr; s2[t].y = aii;
    __syncthreads();
    if (t < 256) {
      const float xre = s2[t].x + s2[t+256].x + s2[t+512].x + s2[t+768].x;
      const float xim = s2[t].y + s2[t+256].y + s2[t+512].y + s2[t+768].y;
      ws[OF_XS_RE + img*256 + t] = xre;
      ws[OF_XS_IM + img*256 + t] = xim;
    }
  }

  __threadfence();
  grid.sync();

  // ================= phase 2: channel mix (block = (o, mc)) =================
  if (t < 256) {
    const int o  = bid & 63;
    const int mc = bid >> 6;
    const int b  = t >> 6;
    const int m  = (mc << 6) + (t & 63);
    const float* xsr = ws + OF_XS_RE;
    const float* xsi = ws + OF_XS_IM;
    float a1r=0.f, a1i=0.f, a2r=0.f, a2i=0.f;
#pragma unroll 4
    for (int i = 0; i < NCI; ++i) {
      const float xr = xsr[((b*NCI + i) << 8) + m];
      const float xi = xsi[((b*NCI + i) << 8) + m];
      const int wi = ((i*NCO + o) << 8) + m;
      const float pw = w1r[wi], q = w1i[wi], u = w2r[wi], v = w2i[wi];
      a1r += xr*pw - xi*q;
      a1i += xr*q + xi*pw;
      a2r += xr*u - xi*v;
      a2i += xr*v + xi*u;
    }
    const int oi = ((b*NCO + o) << 8) + m;
    ws[OF_O1_RE + oi] = a1r;
    ws[OF_O1_IM + oi] = a1i;
    ws[OF_O2_RE + oi] = a2r;
    ws[OF_O2_IM + oi] = a2i;
  }

  __threadfence();
  grid.sync();

  // ================= phase 3: inverse DFT + write out (bo = bid) =================
  {
    float* o1r = L;            // 256
    float* o1i = L + 256;
    float* o2r = L + 512;
    float* o2i = L + 768;
    float* Sr  = L + 1024;     // [256][20]
    float* Si  = L + 6144;     // [256][20]
    float* cst = L + 11264;
    float* snt = L + 11520;
    const int bo = bid;

    __syncthreads();           // phase-1/2 LDS reads fully done (paranoia)
    if (t < 256) {
      o1r[t] = ws[OF_O1_RE + bo*256 + t];
      o1i[t] = ws[OF_O1_IM + bo*256 + t];
      o2r[t] = ws[OF_O2_RE + bo*256 + t];
      o2i[t] = ws[OF_O2_IM + bo*256 + t];
      const float a = TPF * (float)t * (1.0f/256.0f);
      cst[t] = cosf(a);
      snt[t] = sinf(a);
    }
    __syncthreads();

    // ---- phase A: thread (h = t>>2, kq = t&3) -> S[h][kq*4..+3] ----
    {
      const int h  = t >> 2, kq = t & 3;
      const float chh = cst[h], shh = snt[h];
      float c1 = 1.f, s1 = 0.f;
      const int m2i = (240 * h) & 255;
      float c2 = cst[m2i], s2v = snt[m2i];
      float4 sr = {0.f,0.f,0.f,0.f}, si = {0.f,0.f,0.f,0.f};
      for (int j = 0; j < 16; ++j) {
        const float4 r1 = *(const float4*)&o1r[j*16 + kq*4];
        const float4 i1 = *(const float4*)&o1i[j*16 + kq*4];
        const float4 r2 = *(const float4*)&o2r[j*16 + kq*4];
        const float4 i2 = *(const float4*)&o2i[j*16 + kq*4];
        sr.x += r1.x*c1 - i1.x*s1 + r2.x*c2 - i2.x*s2v;
        si.x += r1.x*s1 + i1.x*c1 + r2.x*s2v + i2.x*c2;
        sr.y += r1.y*c1 - i1.y*s1 + r2.y*c2 - i2.y*s2v;
        si.y += r1.y*s1 + i1.y*c1 + r2.y*s2v + i2.y*c2;
        sr.z += r1.z*c1 - i1.z*s1 + r2.z*c2 - i2.z*s2v;
        si.z += r1.z*s1 + i1.z*c1 + r2.z*s2v + i2.z*c2;
        sr.w += r1.w*c1 - i1.w*s1 + r2.w*c2 - i2.w*s2v;
        si.w += r1.w*s1 + i1.w*c1 + r2.w*s2v + i2.w*c2;
        const float n1c = c1*chh - s1*shh, n1s = s1*chh + c1*shh;
        const float n2c = c2*chh - s2v*shh, n2s = s2v*chh + c2*shh;
        c1 = n1c; s1 = n1s; c2 = n2c; s2v = n2s;
      }
      *(float4*)&Sr[h*20 + kq*4] = sr;
      *(float4*)&Si[h*20 + kq*4] = si;
    }
    __syncthreads();

    // ---- phase B: radix-4 butterfly over ky mod 4 ----
    const int w0 = t & 63, rg = t >> 6;     // 16 row-groups x 16 rows
    float c[15], s[15];
#pragma unroll
    for (int k = 0; k < 15; ++k) {
      const int mi = ((k+1) * w0) & 255;
      c[k] = cst[mi];
      s[k] = snt[mi];
    }
    const float scale = 2.0f / 65536.0f;
    const size_t rowbase = ((size_t)bo*256 + rg*16) * 256;
#pragma unroll 2
    for (int r = 0; r < 16; ++r) {
      const int hl = rg*16 + r;
      const float4 a0 = *(const float4*)&Sr[hl*20 + 0];
      const float4 a1 = *(const float4*)&Sr[hl*20 + 4];
      const float4 a2 = *(const float4*)&Sr[hl*20 + 8];
      const float4 a3 = *(const float4*)&Sr[hl*20 + 12];
      const float4 b0 = *(const float4*)&Si[hl*20 + 0];
      const float4 b1 = *(const float4*)&Si[hl*20 + 4];
      const float4 b2 = *(const float4*)&Si[hl*20 + 8];
      const float4 b3 = *(const float4*)&Si[hl*20 + 12];

      float PA = 0.5f * a0.x;
      float PB = 0.f, PC = 0.f, PD = 0.f, QB = 0.f, QD = 0.f;
      PB += a0.y*c[0] - b0.y*s[0];   QB += a0.y*s[0] + b0.y*c[0];
      PC += a0.z*c[1] - b0.z*s[1];
      PD += a0.w*c[2] - b0.w*s[2];   QD += a0.w*s[2] + b0.w*c[2];
      PA += a1.x*c[3] - b1.x*s[3];
      PB += a1.y*c[4] - b1.y*s[4];   QB += a1.y*s[4] + b1.y*c[4];
      PC += a1.z*c[5] - b1.z*s[5];
      PD += a1.w*c[6] - b1.w*s[6];   QD += a1.w*s[6] + b1.w*c[6];
      PA += a2.x*c[7] - b2.x*s[7];
      PB += a2.y*c[8] - b2.y*s[8];   QB += a2.y*s[8] + b2.y*c[8];
      PC += a2.z*c[9] - b2.z*s[9];
      PD += a2.w*c[10] - b2.w*s[10]; QD += a2.w*s[10] + b2.w*c[10];
      PA += a3.x*c[11] - b3.x*s[11];
      PB += a3.y*c[12] - b3.y*s[12]; QB += a3.y*s[12] + b3.y*c[12];
      PC += a3.z*c[13] - b3.z*s[13];
      PD += a3.w*c[14] - b3.w*s[14]; QD += a3.w*s[14] + b3.w*c[14];

      const float T1 = PA + PC, T2 = PB + PD;
      const float T3 = PA - PC, T4 = QB - QD;
      const size_t ob = rowbase + (size_t)r*256 + w0;
      out[ob]       = (T1 + T2) * scale;
      out[ob + 64]  = (T3 - T4) * scale;
      out[ob + 128] = (T1 - T2) * scale;
      out[ob + 192] = (T3 + T4) * scale;
    }
  }
}

extern "C" void kernel_launch(void* const* d_in, const int* in_sizes, int n_in,
                              void* d_out, int out_size, void* d_ws, size_t ws_size,
                              hipStream_t stream) {
  const float* x   = (const float*)d_in[0];
  const float* w1r = (const float*)d_in[1];
  const float* w1i = (const float*)d_in[2];
  const float* w2r = (const float*)d_in[3];
  const float* w2i = (const float*)d_in[4];
  float* out = (float*)d_out;
  float* ws  = (float*)d_ws;

  void* args[] = {(void*)&x, (void*)&w1r, (void*)&w1i, (void*)&w2r,
                  (void*)&w2i, (void*)&ws, (void*)&out};
  hipLaunchCooperativeKernel((const void*)mega, dim3(256), dim3(1024),
                             args, 0, stream);
}

// Round 13
// 65.022 us; speedup vs baseline: 4.5583x; 4.5583x over previous
//
#include <hip/hip_runtime.h>

#define NB 4
#define NCI 64
#define NCO 64
#define PLANE 65536

// workspace offsets (in floats)
#define OF_COS 0
#define OF_SIN 256
#define OF_TW  512                      // [30][256] final-stage trig (ky=1..15 cos/sin)
#define OF_XS_RE (16384 + 32*PLANE)
#define OF_XS_IM (OF_XS_RE + PLANE)
#define OF_O1_RE (OF_XS_IM + PLANE)
#define OF_O1_IM (OF_O1_RE + PLANE)
#define OF_O2_RE (OF_O1_IM + PLANE)
#define OF_O2_IM (OF_O2_RE + PLANE)

// stage1 LDS plane layout
#define XEOFF(w) ((w)*260)
#define XOOFF(w) (16*260 + 8 + (w)*260)

// grid 31: block 0 -> cos/sin tables; blocks 1..30 -> one TW row each
__global__ __launch_bounds__(256) void k0_init(float* __restrict__ ws) {
  const int t = threadIdx.x, b = blockIdx.x;
  const double TP = 6.283185307179586;
  if (b == 0) {
    double a = TP * t / 256.0;
    ws[OF_COS + t] = (float)cos(a);
    ws[OF_SIN + t] = (float)sin(a);
  } else {
    const int p = b - 1;              // 0..29
    const int ky = (p >> 1) + 1;
    double a = TP * ((ky * t) & 255) / 256.0;
    ws[OF_TW + p*256 + t] = (p & 1) ? (float)sin(a) : (float)cos(a);
  }
}

// Fused stage 1+2, 1024 threads, grid 256 (R9-verbatim, best measured).
__global__ __launch_bounds__(1024) void k12_dft(const float* __restrict__ x,
                                                float* __restrict__ ws) {
  __shared__ float buf[8336];
  __shared__ float cst[256], snt[256];
  __shared__ float2 s2[1024];
  const int t = threadIdx.x;
  const int img = blockIdx.x;

  if (t < 256) { cst[t] = ws[OF_COS + t]; snt[t] = ws[OF_SIN + t]; }

  const int sl = t & 3, row = t >> 2;
  const int wq = t & 3, p = (t >> 2) & 1;
  const int kg = (t >> 3) & 1, tr = t >> 4;
  int kyv[4];
#pragma unroll
  for (int j = 0; j < 4; ++j) kyv[j] = p + 8*kg + 2*j;

  __syncthreads();

  float cd[4], sd[4];
#pragma unroll
  for (int j = 0; j < 4; ++j) { cd[j] = cst[kyv[j]]; sd[j] = snt[kyv[j]]; }

  float ar[4][4], ai[4][4];
#pragma unroll
  for (int j = 0; j < 4; ++j)
#pragma unroll
    for (int r = 0; r < 4; ++r) { ar[j][r] = 0.f; ai[j][r] = 0.f; }

  const float* xb = x + (size_t)img * 65536;
  float4 lo = *(const float4*)(xb + row*256 + sl*4);
  float4 hi = *(const float4*)(xb + row*256 + 128 + sl*4);

  const int pbase = p ? (16*260 + 8) : 0;

  for (int c = 0; c < 8; ++c) {
    __syncthreads();
    buf[XEOFF(sl*4+0) + row] = lo.x + hi.x;
    buf[XEOFF(sl*4+1) + row] = lo.y + hi.y;
    buf[XEOFF(sl*4+2) + row] = lo.z + hi.z;
    buf[XEOFF(sl*4+3) + row] = lo.w + hi.w;
    buf[XOOFF(sl*4+0) + row] = lo.x - hi.x;
    buf[XOOFF(sl*4+1) + row] = lo.y - hi.y;
    buf[XOOFF(sl*4+2) + row] = lo.z - hi.z;
    buf[XOOFF(sl*4+3) + row] = lo.w - hi.w;
    __syncthreads();
    if (c < 7) {
      const int w0n = (c+1) * 16;
      lo = *(const float4*)(xb + row*256 + w0n + sl*4);
      hi = *(const float4*)(xb + row*256 + w0n + 128 + sl*4);
    }
    float cc[4], sv[4];
#pragma unroll
    for (int j = 0; j < 4; ++j) {
      const int m = (kyv[j] * (c*16 + wq*4)) & 255;
      cc[j] = cst[m];
      sv[j] = snt[m];
    }
#pragma unroll
    for (int i = 0; i < 4; ++i) {
      const int wl = wq*4 + i;
      const float4 xs4 = *(const float4*)&buf[pbase + wl*260 + tr*4];
#pragma unroll
      for (int j = 0; j < 4; ++j) {
        ar[j][0] += xs4.x * cc[j];  ai[j][0] -= xs4.x * sv[j];
        ar[j][1] += xs4.y * cc[j];  ai[j][1] -= xs4.y * sv[j];
        ar[j][2] += xs4.z * cc[j];  ai[j][2] -= xs4.z * sv[j];
        ar[j][3] += xs4.w * cc[j];  ai[j][3] -= xs4.w * sv[j];
        const float nc = cc[j]*cd[j] - sv[j]*sd[j];
        const float ns = sv[j]*cd[j] + cc[j]*sd[j];
        cc[j] = nc; sv[j] = ns;
      }
    }
  }

#pragma unroll
  for (int j = 0; j < 4; ++j)
#pragma unroll
    for (int r = 0; r < 4; ++r) {
      ar[j][r] += __shfl_xor(ar[j][r], 1);
      ar[j][r] += __shfl_xor(ar[j][r], 2);
      ai[j][r] += __shfl_xor(ai[j][r], 1);
      ai[j][r] += __shfl_xor(ai[j][r], 2);
    }
  __syncthreads();
  if (wq == 0) {
#pragma unroll
    for (int j = 0; j < 4; ++j) {
      const int ky = kyv[j];
      float4 sr; sr.x = ar[j][0]; sr.y = ar[j][1]; sr.z = ar[j][2]; sr.w = ar[j][3];
      float4 si; si.x = ai[j][0]; si.y = ai[j][1]; si.z = ai[j][2]; si.w = ai[j][3];
      *(float4*)&buf[XEOFF(ky) + tr*4] = sr;
      *(float4*)&buf[XOOFF(ky) + tr*4] = si;
    }
  }
  __syncthreads();

  const int ky2 = t & 15, kx = (t >> 4) & 15, hh = t >> 8;
  const float cdk = cst[kx], sdk = snt[kx];
  const int m0 = (kx * hh * 64) & 255;
  float cR = cst[m0], sR = snt[m0];
  float arr = 0.f, aii = 0.f;
  const int be = XEOFF(ky2) + hh*64;
  const int bo = XOOFF(ky2) + hh*64;
#pragma unroll 4
  for (int hq = 0; hq < 16; ++hq) {
    const float4 xr = *(const float4*)&buf[be + hq*4];
    const float4 xi = *(const float4*)&buf[bo + hq*4];
    {
      arr += xr.x*cR + xi.x*sR;  aii += xi.x*cR - xr.x*sR;
      const float nc = cR*cdk - sR*sdk, ns = sR*cdk + cR*sdk; cR = nc; sR = ns;
    }
    {
      arr += xr.y*cR + xi.y*sR;  aii += xi.y*cR - xr.y*sR;
      const float nc = cR*cdk - sR*sdk, ns = sR*cdk + cR*sdk; cR = nc; sR = ns;
    }
    {
      arr += xr.z*cR + xi.z*sR;  aii += xi.z*cR - xr.z*sR;
      const float nc = cR*cdk - sR*sdk, ns = sR*cdk + cR*sdk; cR = nc; sR = ns;
    }
    {
      arr += xr.w*cR + xi.w*sR;  aii += xi.w*cR - xr.w*sR;
      const float nc = cR*cdk - sR*sdk, ns = sR*cdk + cR*sdk; cR = nc; sR = ns;
    }
  }
  s2[t].x = arr; s2[t].y = aii;
  __syncthreads();
  if (t < 256) {
    float xre = s2[t].x + s2[t+256].x + s2[t+512].x + s2[t+768].x;
    float xim = s2[t].y + s2[t+256].y + s2[t+512].y + s2[t+768].y;
    ws[OF_XS_RE + img*256 + t] = xre;
    ws[OF_XS_IM + img*256 + t] = xim;
  }
}

// Stage 3: o1/o2[b,o,m] = sum_i xs[b,i,m] * (wr + i wi)[i,o,m]
__global__ __launch_bounds__(256) void k3_mix(const float* __restrict__ w1r,
    const float* __restrict__ w1i, const float* __restrict__ w2r,
    const float* __restrict__ w2i, float* __restrict__ ws) {
  const int o  = blockIdx.x;     // 0..63
  const int mc = blockIdx.y;     // 0..3
  const int t  = threadIdx.x;    // 256
  const int b  = t >> 6;
  const int m  = (mc << 6) + (t & 63);
  const float* xsr = ws + OF_XS_RE;
  const float* xsi = ws + OF_XS_IM;
  float a1r=0.f, a1i=0.f, a2r=0.f, a2i=0.f;
#pragma unroll 4
  for (int i = 0; i < NCI; ++i) {
    const float xr = xsr[((b*NCI + i) << 8) + m];
    const float xi = xsi[((b*NCI + i) << 8) + m];
    const int wi = ((i*NCO + o) << 8) + m;
    const float p = w1r[wi], q = w1i[wi], u = w2r[wi], v = w2i[wi];
    a1r += xr*p - xi*q;
    a1i += xr*q + xi*p;
    a2r += xr*u - xi*v;
    a2i += xr*v + xi*u;
  }
  const int oi = ((b*NCO + o) << 8) + m;
  ws[OF_O1_RE + oi] = a1r;
  ws[OF_O1_IM + oi] = a1i;
  ws[OF_O2_RE + oi] = a2r;
  ws[OF_O2_IM + oi] = a2i;
}

// Fused stage 4+5. Phase A: R7-verbatim. Phase B: ROW-PAIRED half-wave —
// lanes 0..31 serve row r, lanes 32..63 row r+1 (2 unique broadcast addrs per
// ds_read_b128 -> LDS instr count halves); each lane covers w in {wl, wl+32}
// x 4 radix-4 quarters; the wl+32 trig set derived once via compile-time
// eighth-turn rotation (theta=(k+1)*pi/4).
__global__ __launch_bounds__(256) void k45_idft(const float* __restrict__ ws,
                                                float* __restrict__ out) {
  __shared__ __align__(16) float o1r[256], o1i[256], o2r[256], o2i[256];
  __shared__ float cst[256], snt[256];
  __shared__ __align__(16) float Sr[64][20], Si[64][20];
  const int t  = threadIdx.x;
  const int bo = blockIdx.x >> 2;
  const int hc = blockIdx.x & 3;

  o1r[t] = ws[OF_O1_RE + bo*256 + t];
  o1i[t] = ws[OF_O1_IM + bo*256 + t];
  o2r[t] = ws[OF_O2_RE + bo*256 + t];
  o2i[t] = ws[OF_O2_IM + bo*256 + t];
  cst[t] = ws[OF_COS + t];
  snt[t] = ws[OF_SIN + t];

  const int wl = t & 31;               // 32 w-lanes per row
  const float* Tw = ws + OF_TW;
  float c[15], s[15], c2[15], s2[15];
#pragma unroll
  for (int k = 0; k < 15; ++k) {
    c[k] = Tw[(2*k)*256 + wl];
    s[k] = Tw[(2*k+1)*256 + wl];
  }
  {
    const float R = 0.70710678118654752f;
#pragma unroll
    for (int k = 0; k < 15; ++k) {
      const int r8 = (k + 1) & 7;      // rotation by (k+1)*pi/4
      switch (r8) {
        case 0: c2[k] =  c[k];            s2[k] =  s[k];            break;
        case 1: c2[k] = (c[k]-s[k])*R;    s2[k] = (s[k]+c[k])*R;    break;
        case 2: c2[k] = -s[k];            s2[k] =  c[k];            break;
        case 3: c2[k] = -(c[k]+s[k])*R;   s2[k] = (c[k]-s[k])*R;    break;
        case 4: c2[k] = -c[k];            s2[k] = -s[k];            break;
        case 5: c2[k] = (s[k]-c[k])*R;    s2[k] = -(c[k]+s[k])*R;   break;
        case 6: c2[k] =  s[k];            s2[k] = -c[k];            break;
        default:c2[k] = (c[k]+s[k])*R;    s2[k] = (s[k]-c[k])*R;    break;
      }
    }
  }
  __syncthreads();

  // ---- phase A (R7-verbatim) ----
  {
    const int hl = t >> 2, kq = t & 3;
    const int h  = hc*64 + hl;
    const float chh = cst[h], shh = snt[h];
    float c1 = 1.f, s1 = 0.f;
    const int m2i = (240 * h) & 255;
    float cB = cst[m2i], sB = snt[m2i];
    float4 sr = {0.f,0.f,0.f,0.f}, si = {0.f,0.f,0.f,0.f};
    for (int j = 0; j < 16; ++j) {
      const float4 r1 = *(const float4*)&o1r[j*16 + kq*4];
      const float4 i1 = *(const float4*)&o1i[j*16 + kq*4];
      const float4 r2 = *(const float4*)&o2r[j*16 + kq*4];
      const float4 i2 = *(const float4*)&o2i[j*16 + kq*4];
      sr.x += r1.x*c1 - i1.x*s1 + r2.x*cB - i2.x*sB;
      si.x += r1.x*s1 + i1.x*c1 + r2.x*sB + i2.x*cB;
      sr.y += r1.y*c1 - i1.y*s1 + r2.y*cB - i2.y*sB;
      si.y += r1.y*s1 + i1.y*c1 + r2.y*sB + i2.y*cB;
      sr.z += r1.z*c1 - i1.z*s1 + r2.z*cB - i2.z*sB;
      si.z += r1.z*s1 + i1.z*c1 + r2.z*sB + i2.z*cB;
      sr.w += r1.w*c1 - i1.w*s1 + r2.w*cB - i2.w*sB;
      si.w += r1.w*s1 + i1.w*c1 + r2.w*sB + i2.w*cB;
      const float n1c = c1*chh - s1*shh, n1s = s1*chh + c1*shh;
      const float n2c = cB*chh - sB*shh, n2s = sB*chh + cB*shh;
      c1 = n1c; s1 = n1s; cB = n2c; sB = n2s;
    }
    *(float4*)&Sr[hl][kq*4] = sr;
    *(float4*)&Si[hl][kq*4] = si;
  }
  __syncthreads();

  // ---- phase B: row-paired, radix-4 butterfly x2 trig sets ----
  const int half = (t >> 5) & 1;       // which row of the pair
  const int wv = t >> 6;               // wave: 16 rows = 8 pairs
  const float scale = 2.0f / 65536.0f;
  const size_t tilebase = ((size_t)bo*256 + hc*64) * 256;
#pragma unroll 2
  for (int pr = 0; pr < 8; ++pr) {
    const int hl = wv*16 + pr*2 + half;
    const float4 a0 = *(const float4*)&Sr[hl][0];
    const float4 a1 = *(const float4*)&Sr[hl][4];
    const float4 a2 = *(const float4*)&Sr[hl][8];
    const float4 a3 = *(const float4*)&Sr[hl][12];
    const float4 b0 = *(const float4*)&Si[hl][0];
    const float4 b1 = *(const float4*)&Si[hl][4];
    const float4 b2 = *(const float4*)&Si[hl][8];
    const float4 b3 = *(const float4*)&Si[hl][12];
    const float re[16] = {a0.x,a0.y,a0.z,a0.w, a1.x,a1.y,a1.z,a1.w,
                          a2.x,a2.y,a2.z,a2.w, a3.x,a3.y,a3.z,a3.w};
    const float im[16] = {b0.x,b0.y,b0.z,b0.w, b1.x,b1.y,b1.z,b1.w,
                          b2.x,b2.y,b2.z,b2.w, b3.x,b3.y,b3.z,b3.w};
    const size_t ob = tilebase + (size_t)hl*256;

#pragma unroll
    for (int g = 0; g < 2; ++g) {      // g=0: trig at wl; g=1: at wl+32
      const float* cc = g ? c2 : c;
      const float* ss = g ? s2 : s;
      float PA = 0.5f * re[0];
      float PB = 0.f, PC = 0.f, PD = 0.f, QB = 0.f, QD = 0.f;
#pragma unroll
      for (int k = 0; k < 15; ++k) {
        const int ky = k + 1;
        const float R = re[ky], I = im[ky];
        const int cls = ky & 3;
        if (cls == 0)      PA += R*cc[k] - I*ss[k];
        else if (cls == 1) { PB += R*cc[k] - I*ss[k];  QB += R*ss[k] + I*cc[k]; }
        else if (cls == 2) PC += R*cc[k] - I*ss[k];
        else               { PD += R*cc[k] - I*ss[k];  QD += R*ss[k] + I*cc[k]; }
      }
      const float T1 = PA + PC, T2 = PB + PD;
      const float T3 = PA - PC, T4 = QB - QD;
      const int cb = wl + g*32;
      out[ob + cb]       = (T1 + T2) * scale;
      out[ob + cb + 64]  = (T3 - T4) * scale;
      out[ob + cb + 128] = (T1 - T2) * scale;
      out[ob + cb + 192] = (T3 + T4) * scale;
    }
  }
}

extern "C" void kernel_launch(void* const* d_in, const int* in_sizes, int n_in,
                              void* d_out, int out_size, void* d_ws, size_t ws_size,
                              hipStream_t stream) {
  const float* x   = (const float*)d_in[0];
  const float* w1r = (const float*)d_in[1];
  const float* w1i = (const float*)d_in[2];
  const float* w2r = (const float*)d_in[3];
  const float* w2i = (const float*)d_in[4];
  float* out = (float*)d_out;
  float* ws  = (float*)d_ws;

  hipLaunchKernelGGL(k0_init,  dim3(31),    dim3(256),  0, stream, ws);
  hipLaunchKernelGGL(k12_dft,  dim3(256),   dim3(1024), 0, stream, x, ws);
  hipLaunchKernelGGL(k3_mix,   dim3(64, 4), dim3(256),  0, stream, w1r, w1i, w2r, w2i, ws);
  hipLaunchKernelGGL(k45_idft, dim3(1024),  dim3(256),  0, stream, ws, out);
}